// Round 5
// baseline (636.924 us; speedup 1.0000x reference)
//
#include <hip/hip_runtime.h>
#include <math.h>

#define HIDDEN  512
#define INPUT   8
#define NUM_MIX 2
#define BATCH   64
#define SEQ     2048
#define DD      12
#define KOUT    10
#define TTILE   16
#define NTILES  (SEQ/TTILE)
#define NCW     4            /* consumer waves */
#define BLKT    320          /* 5 waves: 4 consumer + 1 IO */

// h-state kept pre-scaled by 2*log2(e): tanh(h) = 1 - 2*rcp(exp2(h_s)+1)
#define SCALE_F 2.8853900817779268
#define AB_F    0.09765625f  /* alpha*BASE_SCALE/HIDDEN = 50/512 */

typedef float v2f __attribute__((ext_vector_type(2)));
typedef float f4v __attribute__((ext_vector_type(4)));
typedef unsigned int v2u __attribute__((ext_vector_type(2)));

__device__ __forceinline__ v2f pk_fma(v2f a, v2f b, v2f c) {
    return __builtin_elementwise_fma(a, b, c);
}

template<int CTRL>
__device__ __forceinline__ float dpp_add(float x) {
    int y = __builtin_amdgcn_update_dpp(0, __float_as_int(x), CTRL, 0xF, 0xF, true);
    return x + __int_as_float(y);
}
__device__ __forceinline__ float wave_allsum(float x) {
    x = dpp_add<0x111>(x);
    x = dpp_add<0x112>(x);
    x = dpp_add<0x114>(x);
    x = dpp_add<0x118>(x);
    x = dpp_add<0x142>(x);
    x = dpp_add<0x143>(x);
    return __int_as_float(__builtin_amdgcn_readlane(__float_as_int(x), 63));
}

// Dual reduction, result left IN LANES: lane31 = sum64(p0), lane63 = sum64(p1).
// (No readlane on the critical path; writer lanes ship straight to LDS.)
__device__ __forceinline__ float allsum2_lanes(float p0, float p1) {
#if __has_builtin(__builtin_amdgcn_permlane32_swap)
    v2u sw = __builtin_amdgcn_permlane32_swap(
        __float_as_uint(p0), __float_as_uint(p1), false, false);
    float z = __uint_as_float(sw.x) + __uint_as_float(sw.y);
    z = dpp_add<0x111>(z);   // row_shr:1
    z = dpp_add<0x112>(z);   // row_shr:2
    z = dpp_add<0x114>(z);   // row_shr:4
    z = dpp_add<0x118>(z);   // row_shr:8  -> lane15/31/47/63 = row sums
    z = dpp_add<0x142>(z);   // row_bcast:15 -> lane31 = S0, lane63 = S1
    return z;
#else
    float v0 = wave_allsum(p0), v1 = wave_allsum(p1);
    return ((threadIdx.x & 63) < 32) ? v0 : v1;
#endif
}

__global__ __launch_bounds__(BLKT) void fsm_rnn_kernel(
    const float* __restrict__ x,          // (B, SEQ, INPUT)
    const float* __restrict__ means,      // (NUM_MIX, DD)
    const float* __restrict__ scale_tril, // (NUM_MIX, DD, DD)
    const float* __restrict__ mixw,       // (NUM_MIX,)
    const float* __restrict__ seeds,      // (4, HIDDEN, DD)
    const int*   __restrict__ cur_seeds,  // (B,)
    float*       __restrict__ out)        // (B, SEQ, KOUT)
{
    __shared__ __align__(16) float xAll[SEQ*INPUT];      // 64KB: whole x[b]
    __shared__ __align__(16) float P2[2][NCW][2];        // per-step wave partials
    __shared__ __align__(16) float IvL[HIDDEN][INPUT];   // 16KB alpha*I (scaled)
    __shared__ float PM0[HIDDEN], PM1[HIDDEN], N0[HIDDEN], N1[HIDDEN]; // 8KB
    __shared__ double Leff[DD*DD];
    __shared__ double meansw[DD];

    const int tid  = threadIdx.x;
    const int lane = tid & 63;
    const int wid  = tid >> 6;
    const int b    = blockIdx.x;
    const int s    = cur_seeds[b];
    const float* xb = x + (size_t)b * SEQ * INPUT;
    float* outb = out + (size_t)b * SEQ * KOUT;

    // ---- mixture weights ----
    double w0 = fmax((double)mixw[0], 1e-6);
    double w1 = fmax((double)mixw[1], 1e-6);
    double wsum = w0 + w1; w0 /= wsum; w1 /= wsum;

    // ---- weighted clamped-tril L, weighted means ----
    if (tid < DD*DD) {
        int d = tid / DD, e = tid % DD;
        double acc = 0.0;
        #pragma unroll
        for (int i = 0; i < NUM_MIX; ++i) {
            float v = scale_tril[i*DD*DD + d*DD + e];
            float c = (d > e) ? v : (d == e ? fabsf(v - 1e-12f) + 1e-12f : 0.0f);
            acc += (i == 0 ? w0 : w1) * (double)c;
        }
        Leff[tid] = acc;
    }
    if (tid < DD)
        meansw[tid] = w0 * (double)means[tid] + w1 * (double)means[DD + tid];

    // ---- stage ENTIRE x[b] into LDS (no global loads in main loop) ----
    {
        const f4v* src = (const f4v*)xb;
        #pragma unroll
        for (int k = 0; k < 13; ++k) {
            int i = tid + k*BLKT;
            if (i < SEQ*INPUT/4)
                *(f4v*)&xAll[i*4] = src[i];
        }
    }
    __syncthreads();

    // ---- per-h params (double), stored pre-scaled (baseline convention) ----
    if (tid < 256) {
        #pragma unroll
        for (int rr = 0; rr < 2; ++rr) {
            int h = tid + rr*256;
            const float* sh = &seeds[(s*HIDDEN + h)*DD];
            double comb[DD];
            #pragma unroll
            for (int d = 0; d < DD; ++d) {
                double acc = meansw[d];
                for (int e = 0; e <= d; ++e)
                    acc += Leff[d*DD + e] * (double)sh[e];
                comb[d] = acc;
            }
            PM0[h] = (float)(SCALE_F * (double)AB_F * comb[0]);
            PM1[h] = (float)(SCALE_F * (double)AB_F * comb[1]);
            N0[h]  = (float)comb[2];
            N1[h]  = (float)comb[3];
            #pragma unroll
            for (int i = 0; i < INPUT; ++i)
                IvL[h][i] = (float)(SCALE_F * 0.1 * comb[4 + i]);
        }
    }
    __syncthreads();

    // ---- per-role persistent state ----
    v2f AM0{}, AM1{}, N0v{}, N1v{}, H{};
    v2f CC[TTILE], CN[TTILE];
    f4v IvAa{}, IvCa{}, IvAb{}, IvCb{};
    float zf = 0.0f, wst = 0.0f;

    if (wid < NCW) {
        const int ha = wid*128 + lane, hb = ha + 64;   // 2 units per lane
        AM0 = (v2f){PM0[ha], PM0[hb]};
        AM1 = (v2f){PM1[ha], PM1[hb]};
        N0v = (v2f){N0[ha],  N0[hb]};
        N1v = (v2f){N1[ha],  N1[hb]};
        H   = (v2f){0.0f, 0.0f};
        IvAa = *(const f4v*)&IvL[ha][0];
        IvCa = *(const f4v*)&IvL[ha][4];
        IvAb = *(const f4v*)&IvL[hb][0];
        IvCb = *(const f4v*)&IvL[hb][4];
    }

    // Ix slice for this lane's 2 units at one timestep (reads x via LDS broadcast)
    auto slice = [&](const float* xsp) -> v2f {
        f4v xa = *(const f4v*)xsp;
        f4v xc = *(const f4v*)(xsp + 4);
        float ca = IvAa.x*xa.x;
        ca = fmaf(IvAa.y, xa.y, ca); ca = fmaf(IvAa.z, xa.z, ca);
        ca = fmaf(IvAa.w, xa.w, ca); ca = fmaf(IvCa.x, xc.x, ca);
        ca = fmaf(IvCa.y, xc.y, ca); ca = fmaf(IvCa.z, xc.z, ca);
        ca = fmaf(IvCa.w, xc.w, ca);
        float cb = IvAb.x*xa.x;
        cb = fmaf(IvAb.y, xa.y, cb); cb = fmaf(IvAb.z, xa.z, cb);
        cb = fmaf(IvAb.w, xa.w, cb); cb = fmaf(IvCb.x, xc.x, cb);
        cb = fmaf(IvCb.y, xc.y, cb); cb = fmaf(IvCb.z, xc.z, cb);
        cb = fmaf(IvCb.w, xc.w, cb);
        return (v2f){ca, cb};
    };

    // prologue: CC for tile 0
    if (wid < NCW) {
        #pragma unroll
        for (int tt = 0; tt < TTILE; ++tt)
            CC[tt] = slice(&xAll[tt*INPUT]);
    }

    for (int T = 0; T < NTILES; ++T) {
        const int base = T*TTILE*INPUT;
        float zbuf[TTILE], wbuf[TTILE];

        #pragma unroll
        for (int tt = 0; tt < TTILE; ++tt) {
            v2f hc{};
            if (wid < NCW) {
                // tanh(H) = 1 - 2*rcp(exp2(H)+1)  (H pre-scaled) — baseline math
                v2f E, A, R, TH;
                E.x = __builtin_amdgcn_exp2f(H.x);
                E.y = __builtin_amdgcn_exp2f(H.y);
                A = E + 1.0f;
                R.x = __builtin_amdgcn_rcpf(A.x);
                R.y = __builtin_amdgcn_rcpf(A.y);
                TH = pk_fma((v2f){-2.0f,-2.0f}, R, (v2f){1.0f,1.0f});
                float p0 = fmaf(TH.y, N0v.y, TH.x*N0v.x);
                float p1 = fmaf(TH.y, N1v.y, TH.x*N1v.x);
                float zr = allsum2_lanes(p0, p1);   // lane31=S0, lane63=S1
                if (lane == 31 || lane == 63)
                    P2[tt & 1][wid][lane >> 5] = zr;
                hc = pk_fma((v2f){0.9f,0.9f}, H, CC[tt]);
            }
            __syncthreads();
            if (wid < NCW) {
                // issue partial reads, hide their latency under the produce slice
                f4v pa = *(const f4v*)&P2[tt & 1][0][0];
                f4v pb = *(const f4v*)&P2[tt & 1][2][0];
                if (T + 1 < NTILES)
                    CN[tt] = slice(&xAll[base + TTILE*INPUT + tt*INPUT]);
                float v0 = (pa.x + pa.z) + (pb.x + pb.z);
                float v1 = (pa.y + pa.w) + (pb.y + pb.w);
                H = pk_fma(AM0, (v2f){v0,v0}, pk_fma(AM1, (v2f){v1,v1}, hc));
            } else {
                if (lane < INPUT) {
                    zf = fmaf(0.9f, zf, 0.1f * xAll[base + tt*INPUT + lane]);
                    zbuf[tt] = zf;
                } else if (lane < 10) {
                    f4v pa = *(const f4v*)&P2[tt & 1][0][0];
                    f4v pb = *(const f4v*)&P2[tt & 1][2][0];
                    float vw = (lane & 1) ? (pa.y + pa.w) + (pb.y + pb.w)
                                          : (pa.x + pa.z) + (pb.x + pb.z);
                    wst = fmaf(0.9f, wst, AB_F * vw);
                    wbuf[tt] = wst;
                }
            }
        }

        // IO: flush this tile's outputs (one store-drain per 16 barriers)
        if (wid == NCW) {
            if (lane < INPUT) {
                #pragma unroll
                for (int tt = 0; tt < TTILE; ++tt)
                    outb[(T*TTILE + tt)*KOUT + 2 + lane] = zbuf[tt];
            } else if (lane < 10) {
                #pragma unroll
                for (int tt = 0; tt < TTILE; ++tt)
                    outb[(T*TTILE + tt)*KOUT + (lane & 1)] = wbuf[tt];
            }
        }
        // consumers: adopt next tile's drive values
        if (wid < NCW && T + 1 < NTILES) {
            #pragma unroll
            for (int tt = 0; tt < TTILE; ++tt) CC[tt] = CN[tt];
        }
    }
}

extern "C" void kernel_launch(void* const* d_in, const int* in_sizes, int n_in,
                              void* d_out, int out_size, void* d_ws, size_t ws_size,
                              hipStream_t stream) {
    (void)d_ws; (void)ws_size;
    const float* x          = (const float*)d_in[0];
    const float* means      = (const float*)d_in[1];
    const float* scale_tril = (const float*)d_in[2];
    const float* mixw       = (const float*)d_in[3];
    const float* seeds      = (const float*)d_in[4];
    const int*   cur_seeds  = (const int*)d_in[5];
    float* out = (float*)d_out;

    fsm_rnn_kernel<<<BATCH, BLKT, 0, stream>>>(
        x, means, scale_tril, mixw, seeds, cur_seeds, out);
}

// Round 6
// 459.776 us; speedup vs baseline: 1.3853x; 1.3853x over previous
//
#include <hip/hip_runtime.h>
#include <math.h>

#define HIDDEN  512
#define INPUT   8
#define NUM_MIX 2
#define BATCH   64
#define SEQ     2048
#define DD      12
#define KOUT    10
#define TTILE   16
#define NTILES  (SEQ/TTILE)

#define AB_F    0.09765625f   /* alpha*BASE_SCALE/HIDDEN = 50/512 */
#define SCL_F   2.8853900817779268f  /* 2*log2(e): tanh(h)=1-2/(exp2(SCL*h)+1) */

typedef float v2f __attribute__((ext_vector_type(2)));
typedef float f4v __attribute__((ext_vector_type(4)));
typedef unsigned int v2u __attribute__((ext_vector_type(2)));

__device__ __forceinline__ v2f pk_fma(v2f a, v2f b, v2f c) {
    return __builtin_elementwise_fma(a, b, c);
}

template<int CTRL>
__device__ __forceinline__ float dpp_add(float x) {
    int y = __builtin_amdgcn_update_dpp(0, __float_as_int(x), CTRL, 0xF, 0xF, true);
    return x + __int_as_float(y);
}
__device__ __forceinline__ float wave_allsum(float x) {
    x = dpp_add<0x111>(x);   // row_shr:1
    x = dpp_add<0x112>(x);   // row_shr:2
    x = dpp_add<0x114>(x);   // row_shr:4
    x = dpp_add<0x118>(x);   // row_shr:8
    x = dpp_add<0x142>(x);   // row_bcast:15
    x = dpp_add<0x143>(x);   // row_bcast:31
    return __int_as_float(__builtin_amdgcn_readlane(__float_as_int(x), 63));
}

// Fused dual reduction: v0 = sum64(p0), v1 = sum64(p1).
__device__ __forceinline__ void allsum2(float p0, float p1,
                                        float& v0, float& v1) {
#if __has_builtin(__builtin_amdgcn_permlane32_swap)
    v2u sw = __builtin_amdgcn_permlane32_swap(
        __float_as_uint(p0), __float_as_uint(p1), false, false);
    float z = __uint_as_float(sw.x) + __uint_as_float(sw.y);
    z = dpp_add<0x111>(z);   // row_shr:1
    z = dpp_add<0x112>(z);   // row_shr:2
    z = dpp_add<0x114>(z);   // row_shr:4
    z = dpp_add<0x118>(z);   // row_shr:8  -> lane15/31/47/63 = row sums
    z = dpp_add<0x142>(z);   // row_bcast:15 -> lane31 = S0, lane63 = S1
    v0 = __int_as_float(__builtin_amdgcn_readlane(__float_as_int(z), 31));
    v1 = __int_as_float(__builtin_amdgcn_readlane(__float_as_int(z), 63));
#else
    v0 = wave_allsum(p0);
    v1 = wave_allsum(p1);
#endif
}

__global__ __launch_bounds__(256) void fsm_rnn_kernel(
    const float* __restrict__ x,          // (B, SEQ, INPUT)
    const float* __restrict__ means,      // (NUM_MIX, DD)
    const float* __restrict__ scale_tril, // (NUM_MIX, DD, DD)
    const float* __restrict__ mixw,       // (NUM_MIX,)
    const float* __restrict__ seeds,      // (4, HIDDEN, DD)
    const int*   __restrict__ cur_seeds,  // (B,)
    float*       __restrict__ out)        // (B, SEQ, KOUT)
{
    // IxP pair-layout: [dbuf][tt][q][lane][pr] holds unit h = lane + 64*(2q+pr)
    __shared__ __align__(16) float IxP[2][TTILE][4][64][2];  // 64KB
    __shared__ __align__(16) float xsB[2][TTILE*INPUT];      // 1KB raw x tiles
    __shared__ __align__(16) float IvL[HIDDEN][INPUT];       // 16KB alpha*I
    __shared__ float PM0[HIDDEN], PM1[HIDDEN], N0[HIDDEN], N1[HIDDEN]; // 8KB
    __shared__ __align__(8) float vr2[2][TTILE][64][2];      // 16KB per-lane v copies
    __shared__ double Leff[DD*DD];
    __shared__ double meansw[DD];

    const int tid  = threadIdx.x;
    const int lane = tid & 63;
    const int wid  = tid >> 6;
    const int b    = blockIdx.x;
    const int s    = cur_seeds[b];
    const float* xb = x + (size_t)b * SEQ * INPUT;
    float* outb = out + (size_t)b * SEQ * KOUT;

    // ---- mixture weights ----
    double w0 = fmax((double)mixw[0], 1e-6);
    double w1 = fmax((double)mixw[1], 1e-6);
    double wsum = w0 + w1; w0 /= wsum; w1 /= wsum;

    // ---- weighted clamped-tril L, weighted means ----
    if (tid < DD*DD) {
        int d = tid / DD, e = tid % DD;
        double acc = 0.0;
        #pragma unroll
        for (int i = 0; i < NUM_MIX; ++i) {
            float v = scale_tril[i*DD*DD + d*DD + e];
            float c = (d > e) ? v : (d == e ? fabsf(v - 1e-12f) + 1e-12f : 0.0f);
            acc += (i == 0 ? w0 : w1) * (double)c;
        }
        Leff[tid] = acc;
    }
    if (tid < DD)
        meansw[tid] = w0 * (double)means[tid] + w1 * (double)means[DD + tid];
    if (tid < 2*TTILE*INPUT)
        ((float*)xsB)[tid] = xb[tid];          // stage x tiles 0,1
    __syncthreads();

    // ---- per-h params (double), natural units ----
    #pragma unroll
    for (int rr = 0; rr < 2; ++rr) {
        int h = tid + rr*256;
        const float* sh = &seeds[(s*HIDDEN + h)*DD];
        double comb[DD];
        #pragma unroll
        for (int d = 0; d < DD; ++d) {
            double acc = meansw[d];
            for (int e = 0; e <= d; ++e)
                acc += Leff[d*DD + e] * (double)sh[e];
            comb[d] = acc;
        }
        PM0[h] = (float)((double)AB_F * comb[0]);
        PM1[h] = (float)((double)AB_F * comb[1]);
        N0[h]  = (float)comb[2];
        N1[h]  = (float)comb[3];
        #pragma unroll
        for (int i = 0; i < INPUT; ++i)
            IvL[h][i] = (float)(0.1 * comb[4 + i]);
    }
    __syncthreads();

    // ---- persistent per-role state ----
    // Consumer carries T = tanh(H), S = 1 - T^2 as state:
    //   incremental (2nd-order exact): T += d*S*(1 - d*T), d = Hn - H
    //   exact resync via exp2/rcp once per tile (tt==0) kills drift.
    v2f AM0[4], AM1[4], NN0v[4], NN1v[4], H[4], T[4], S[4];
    f4v IvA[3], IvC[3];
    float zf = 0.0f, wst = 0.0f;
    const int pid = (wid - 1)*64 + lane;   // producer id 0..191
    const int zi  = lane - 56;

    if (wid == 0) {
        // consumer owns h = lane + 64*m; pair q = m>>1, pr = m&1
        #pragma unroll
        for (int q = 0; q < 4; ++q) {
            int ha = lane + 64*(2*q), hb = lane + 64*(2*q + 1);
            AM0[q]  = (v2f){PM0[ha], PM0[hb]};
            AM1[q]  = (v2f){PM1[ha], PM1[hb]};
            NN0v[q] = (v2f){N0[ha],  N0[hb]};
            NN1v[q] = (v2f){N1[ha],  N1[hb]};
            H[q]    = (v2f){0.0f, 0.0f};
            T[q]    = (v2f){0.0f, 0.0f};   // tanh(0)
            S[q]    = (v2f){1.0f, 1.0f};   // sech^2(0)
        }
    } else {
        #pragma unroll
        for (int q = 0; q < 3; ++q) {
            int h = pid + 192*q;
            if (h < HIDDEN) {
                IvA[q] = *(const f4v*)&IvL[h][0];
                IvC[q] = *(const f4v*)&IvL[h][4];
            }
        }
    }

    // producer: fill IxP tile tg; wave1 lanes 56-63 emit the z-filter outputs
    auto produce = [&](int tg) {
        const int pb = tg & 1;
        const float* xs = xsB[pb];
        for (int tt = 0; tt < TTILE; ++tt) {
            f4v xa = *(const f4v*)&xs[tt*INPUT];
            f4v xc = *(const f4v*)&xs[tt*INPUT + 4];
            #pragma unroll
            for (int q = 0; q < 3; ++q) {
                int h = pid + 192*q;
                if (h < HIDDEN) {
                    float v =      IvA[q].x * xa.x;
                    v = fmaf(IvA[q].y, xa.y, v);
                    v = fmaf(IvA[q].z, xa.z, v);
                    v = fmaf(IvA[q].w, xa.w, v);
                    v = fmaf(IvC[q].x, xc.x, v);
                    v = fmaf(IvC[q].y, xc.y, v);
                    v = fmaf(IvC[q].z, xc.z, v);
                    v = fmaf(IvC[q].w, xc.w, v);
                    IxP[pb][tt][(h >> 7)][h & 63][(h >> 6) & 1] = v;
                }
            }
        }
        if (wid == 1 && lane >= 56) {
            #pragma unroll 4
            for (int tt = 0; tt < TTILE; ++tt) {
                zf = fmaf(0.9f, zf, 0.1f * xs[tt*INPUT + zi]);
                outb[(tg*TTILE + tt)*KOUT + 2 + zi] = zf;
            }
        }
    };

    // w-EMA for cols 0,1 (wave 1, lanes 54,55) — reads lane 0's v copy
    auto process_w = [&](int tile) {
        if (lane == 54 || lane == 55) {
            const int widx = lane & 1;
            for (int tt = 0; tt < TTILE; ++tt) {
                wst = fmaf(0.9f, wst, AB_F * vr2[tile & 1][tt][0][widx]);
                outb[(tile*TTILE + tt)*KOUT + widx] = wst;
            }
        }
    };

    if (wid != 0) produce(0);
    __syncthreads();

    for (int Tt = 0; Tt < NTILES; ++Tt) {
        if (wid == 0) {
            const int pb = Tt & 1;
            v2f CC[4], CN[4];
            #pragma unroll
            for (int q = 0; q < 4; ++q)
                CC[q] = *(const v2f*)&IxP[pb][0][q][lane][0];
            #pragma unroll
            for (int tt = 0; tt < TTILE; ++tt) {
                if (tt < TTILE-1) {            // b64 prefetch, 2-way banks = free
                    #pragma unroll
                    for (int q = 0; q < 4; ++q)
                        CN[q] = *(const v2f*)&IxP[pb][tt+1][q][lane][0];
                }
                // dots straight from carried T = tanh(H_{t-1}) — no trans ops
                v2f a0 = T[0]*NN0v[0]; a0 = pk_fma(T[1], NN0v[1], a0);
                v2f b0 = T[2]*NN0v[2]; b0 = pk_fma(T[3], NN0v[3], b0);
                v2f a1 = T[0]*NN1v[0]; a1 = pk_fma(T[1], NN1v[1], a1);
                v2f b1 = T[2]*NN1v[2]; b1 = pk_fma(T[3], NN1v[3], b1);
                v2f s0 = a0 + b0, s1 = a1 + b1;
                float p0 = s0.x + s0.y;
                float p1 = s1.x + s1.y;

                float v0, v1;
                allsum2(p0, p1, v0, v1);   // fused dual reduction (permlane32)

                const v2f nine = {0.9f, 0.9f};
                const v2f one  = {1.0f, 1.0f};
                v2f v0v = {v0, v0}, v1v = {v1, v1};
                #pragma unroll
                for (int q = 0; q < 4; ++q) {
                    v2f hc = pk_fma(nine, H[q], CC[q]);
                    v2f Hn = pk_fma(AM0[q], v0v, pk_fma(AM1[q], v1v, hc));
                    if (tt == 0) {
                        // exact resync: T = tanh(Hn) via exp2/rcp (once/tile)
                        v2f E, A, R;
                        E.x = __builtin_amdgcn_exp2f(SCL_F * Hn.x);
                        E.y = __builtin_amdgcn_exp2f(SCL_F * Hn.y);
                        A = E + 1.0f;
                        R.x = __builtin_amdgcn_rcpf(A.x);
                        R.y = __builtin_amdgcn_rcpf(A.y);
                        T[q] = pk_fma((v2f){-2.0f,-2.0f}, R, one);
                    } else {
                        // 2nd-order incremental: T += d*S*(1 - d*T)
                        v2f d = Hn - H[q];
                        v2f u = d * S[q];
                        v2f w = pk_fma(-d, T[q], one);
                        T[q]  = pk_fma(u, w, T[q]);
                    }
                    S[q] = pk_fma(-T[q], T[q], one);   // 1 - T^2
                    H[q] = Hn;
                }

                // unconditional per-lane copy (identical values) — no exec games
                *(v2f*)&vr2[pb][tt][lane][0] = (v2f){v0, v1};

                #pragma unroll
                for (int q = 0; q < 4; ++q) CC[q] = CN[q];
            }
        } else {
            if (Tt + 1 < NTILES) produce(Tt + 1);
            if (wid == 2 && Tt + 2 < NTILES) {
                const int base = (Tt + 2)*(TTILE*INPUT);
                xsB[Tt & 1][lane]      = xb[base + lane];
                xsB[Tt & 1][lane + 64] = xb[base + lane + 64];
            }
            if (wid == 1 && Tt >= 1) process_w(Tt - 1);
        }
        __syncthreads();
    }
    if (wid == 1) process_w(NTILES - 1);
}

extern "C" void kernel_launch(void* const* d_in, const int* in_sizes, int n_in,
                              void* d_out, int out_size, void* d_ws, size_t ws_size,
                              hipStream_t stream) {
    (void)d_ws; (void)ws_size;
    const float* x          = (const float*)d_in[0];
    const float* means      = (const float*)d_in[1];
    const float* scale_tril = (const float*)d_in[2];
    const float* mixw       = (const float*)d_in[3];
    const float* seeds      = (const float*)d_in[4];
    const int*   cur_seeds  = (const int*)d_in[5];
    float* out = (float*)d_out;

    fsm_rnn_kernel<<<BATCH, 256, 0, stream>>>(
        x, means, scale_tril, mixw, seeds, cur_seeds, out);
}